// Round 8
// baseline (393.621 us; speedup 1.0000x reference)
//
#include <hip/hip_runtime.h>
#include <math.h>

#define Bb 128
#define Tt 1024
#define Ll 96

typedef float v2f __attribute__((ext_vector_type(2)));
typedef float v4f __attribute__((ext_vector_type(4)));

// One block = one batch = TWO waves running INDEPENDENT halves of the chain
// (round 7, kept: 1023 -> 512 serial steps):
//   wave 0 (forward):  q_t = (E^T q_{t-1}) o w_t,  t = 1..511
//   wave 1 (backward): v_{t-1} = E (v_t o w_t),    t = 1023..512, v_1023 = 1
// Meeting point: log_norm = log(v_511 . q_511) + (Dk_f + Dk_b)*ln2.
//
// Round-8 step change: q distribution via LDS BROADCAST reads instead of 96
// v_readlane (readlane ~4cy issue: 384 cy/step just to distribute). Now:
// 1 ds_write_b64 + 24 uniform-address ds_read_b128 (broadcast: no 64-lane
// serialization) on the LDS pipe, overlapped with 96 v_pk_fma_f32 (v2f
// accumulators pack the lane's two output columns). Off-path work (exp,
// prefetch, exponent bookkeeping) sits between write and reads to absorb the
// turnaround. Same-wave LDS is in-order in HW; asm "memory" clobbers stop the
// compiler from hoisting reads above the write. No barriers in the loop.
__global__ __launch_bounds__(128, 1)
__attribute__((amdgpu_waves_per_eu(1)))
void crf_fwd_kernel(
    const float* __restrict__ inputs,      // (B, T, L) fp32
    const int*   __restrict__ labels_idx,  // (B, T) int32
    const float* __restrict__ trans,       // (L, L) fp32
    float*       __restrict__ out)         // (B, 1) fp32
{
    const int b    = blockIdx.x;
    const int tid  = threadIdx.x;                    // 0..127
    const int wave = tid >> 6;
    const int i    = tid & 63;                       // lane
    const int col  = (2 * i < Ll) ? 2 * i : (Ll - 2); // clamp lanes 48..63

    __shared__ __align__(16) float qbuf[2][Ll];  // fwd double buffer (parity)
    __shared__ __align__(16) float sbuf[Ll];     // bwd single buffer
    __shared__ __align__(16) float uex[Ll];      // backward v_511
    __shared__ float wps[2];                     // per-wave score partials
    __shared__ int   dks[2];                     // per-wave Dk

    const float* xbase = inputs + (size_t)b * Tt * Ll;

    // ---- point_score + trans_score, split across both waves ----
    float ps = 0.f;
    {
        const int* lb = labels_idx + b * Tt;
        #pragma unroll 4
        for (int t = tid; t < Tt; t += 128) {
            int i0 = lb[t];
            ps += xbase[t * Ll + i0];
            if (t < Tt - 1) ps += trans[i0 * Ll + lb[t + 1]];
        }
        #pragma unroll
        for (int off = 32; off; off >>= 1) ps += __shfl_xor(ps, off, 64);
        if (i == 0) wps[wave] = ps;
    }

#define EROWS(X) \
    X(0)  X(1)  X(2)  X(3)  X(4)  X(5)  X(6)  X(7)  X(8)  X(9)  X(10) X(11) \
    X(12) X(13) X(14) X(15) X(16) X(17) X(18) X(19) X(20) X(21) X(22) X(23) \
    X(24) X(25) X(26) X(27) X(28) X(29) X(30) X(31) X(32) X(33) X(34) X(35) \
    X(36) X(37) X(38) X(39) X(40) X(41) X(42) X(43) X(44) X(45) X(46) X(47) \
    X(48) X(49) X(50) X(51) X(52) X(53) X(54) X(55) X(56) X(57) X(58) X(59) \
    X(60) X(61) X(62) X(63) X(64) X(65) X(66) X(67) X(68) X(69) X(70) X(71) \
    X(72) X(73) X(74) X(75) X(76) X(77) X(78) X(79) X(80) X(81) X(82) X(83) \
    X(84) X(85) X(86) X(87) X(88) X(89) X(90) X(91) X(92) X(93) X(94) X(95)

#define EDECL(n) v2f EE##n;

// chunk: one broadcast b128 read feeds 4 pk-FMAs (splat x {colA,colB} pair).
#define CH(j, n0, n1, n2, n3) { v4f q4 = qp[(j)]; \
        acc0 += (v2f){q4.x, q4.x} * EE##n0; \
        acc1 += (v2f){q4.y, q4.y} * EE##n1; \
        acc2 += (v2f){q4.z, q4.z} * EE##n2; \
        acc3 += (v2f){q4.w, q4.w} * EE##n3; }
#define CHALL \
        CH(0,  0,  1,  2,  3)   CH(1,  4,  5,  6,  7)  \
        CH(2,  8,  9,  10, 11)  CH(3,  12, 13, 14, 15) \
        CH(4,  16, 17, 18, 19)  CH(5,  20, 21, 22, 23) \
        CH(6,  24, 25, 26, 27)  CH(7,  28, 29, 30, 31) \
        CH(8,  32, 33, 34, 35)  CH(9,  36, 37, 38, 39) \
        CH(10, 40, 41, 42, 43)  CH(11, 44, 45, 46, 47) \
        CH(12, 48, 49, 50, 51)  CH(13, 52, 53, 54, 55) \
        CH(14, 56, 57, 58, 59)  CH(15, 60, 61, 62, 63) \
        CH(16, 64, 65, 66, 67)  CH(17, 68, 69, 70, 71) \
        CH(18, 72, 73, 74, 75)  CH(19, 76, 77, 78, 79) \
        CH(20, 80, 81, 82, 83)  CH(21, 84, 85, 86, 87) \
        CH(22, 88, 89, 90, 91)  CH(23, 92, 93, 94, 95)

    v2f qv;                // this wave's two owned state elements
    int Dk = 0;

    if (wave == 0) {
        // ================= FORWARD: t = 1..511 =================
        EROWS(EDECL)
        // column layout: EE_n = {E[n][col], E[n][col+1]}
#define EINIT(n) { v2f r_ = *reinterpret_cast<const v2f*>(&trans[(n) * Ll + col]); \
                   EE##n = (v2f){__expf(r_.x), __expf(r_.y)}; \
                   asm volatile("" ::: "memory"); }
        EROWS(EINIT)
#undef EINIT

        v2f x0 = *reinterpret_cast<const v2f*>(&xbase[col]);
        qv = (v2f){__expf(x0.x), __expf(x0.y)};
        if (i < 48) *reinterpret_cast<v2f*>(&qbuf[0][col]) = qv;
        asm volatile("" ::: "memory");
        int gb = __builtin_amdgcn_readfirstlane(__float_as_int(qv.x));
        int   kcur = ((gb >> 23) & 0xff) - 127;
        float r    = __uint_as_float((unsigned)(127 - kcur) << 23);

        v2f x1 = *reinterpret_cast<const v2f*>(&xbase[1 * Ll + col]);
        v2f ew = (v2f){__expf(x1.x), __expf(x1.y)};
        v2f x2 = *reinterpret_cast<const v2f*>(&xbase[2 * Ll + col]);
        v2f x3 = *reinterpret_cast<const v2f*>(&xbase[3 * Ll + col]);
        v2f x4 = *reinterpret_cast<const v2f*>(&xbase[4 * Ll + col]);
        v2f x5 = *reinterpret_cast<const v2f*>(&xbase[5 * Ll + col]);
        v2f x6 = *reinterpret_cast<const v2f*>(&xbase[6 * Ll + col]);
        v2f x7 = *reinterpret_cast<const v2f*>(&xbase[7 * Ll + col]);

        #pragma unroll 1
        for (int t = 1; t <= Tt / 2 - 1; ++t) {
            const int rp = (t - 1) & 1, wp = t & 1;
            Dk += kcur;
            v2f w = ew * r;

            const v4f* qp = reinterpret_cast<const v4f*>(&qbuf[rp][0]);
            v2f acc0 = {0.f,0.f}, acc1 = {0.f,0.f};
            v2f acc2 = {0.f,0.f}, acc3 = {0.f,0.f};
            CHALL
            qv = ((acc0 + acc1) + (acc2 + acc3)) * w;

            if (i < 48) *reinterpret_cast<v2f*>(&qbuf[wp][col]) = qv;
            asm volatile("" ::: "memory");

            // off-path (fills write->read turnaround of next iteration)
            gb   = __builtin_amdgcn_readfirstlane(__float_as_int(qv.x));
            kcur = ((gb >> 23) & 0xff) - 127;
            r    = __uint_as_float((unsigned)(127 - kcur) << 23);
            ew   = (v2f){__expf(x2.x), __expf(x2.y)};
            x2 = x3; x3 = x4; x4 = x5; x5 = x6; x6 = x7;
            int row = t + 7; if (row > Tt - 1) row = Tt - 1;
            x7 = *reinterpret_cast<const v2f*>(&xbase[row * Ll + col]);
        }
        if (i == 0) dks[0] = Dk;
    } else {
        // ================= BACKWARD: t = 1023..512 =================
        // row layout: EE_n = {E[col][n], E[col+1][n]}
        EROWS(EDECL)
#define EINIT(n) { EE##n = (v2f){__expf(trans[col * Ll + (n)]), \
                                 __expf(trans[(col + 1) * Ll + (n)])}; \
                   asm volatile("" ::: "memory"); }
        EROWS(EINIT)
#undef EINIT

        qv = (v2f){1.f, 1.f};                  // v_1023
        int   kcur = 0;
        float r    = 1.f;

        v2f x1 = *reinterpret_cast<const v2f*>(&xbase[(Tt - 1) * Ll + col]);
        v2f ew = (v2f){__expf(x1.x), __expf(x1.y)};
        v2f x2 = *reinterpret_cast<const v2f*>(&xbase[(Tt - 2) * Ll + col]);
        v2f x3 = *reinterpret_cast<const v2f*>(&xbase[(Tt - 3) * Ll + col]);
        v2f x4 = *reinterpret_cast<const v2f*>(&xbase[(Tt - 4) * Ll + col]);
        v2f x5 = *reinterpret_cast<const v2f*>(&xbase[(Tt - 5) * Ll + col]);
        v2f x6 = *reinterpret_cast<const v2f*>(&xbase[(Tt - 6) * Ll + col]);
        v2f x7 = *reinterpret_cast<const v2f*>(&xbase[(Tt - 7) * Ll + col]);

        #pragma unroll 1
        for (int t = Tt - 1; t >= Tt / 2; --t) {
            Dk += kcur;
            v2f s = qv * (ew * r);             // s = v_t o w_t (pre-multiply)

            if (i < 48) *reinterpret_cast<v2f*>(&sbuf[col]) = s;
            asm volatile("" ::: "memory");

            // off-path between write and reads (absorbs the turnaround)
            ew = (v2f){__expf(x2.x), __expf(x2.y)};
            x2 = x3; x3 = x4; x4 = x5; x5 = x6; x6 = x7;
            int row = t - 8; if (row < 0) row = 0;
            x7 = *reinterpret_cast<const v2f*>(&xbase[row * Ll + col]);

            const v4f* qp = reinterpret_cast<const v4f*>(&sbuf[0]);
            v2f acc0 = {0.f,0.f}, acc1 = {0.f,0.f};
            v2f acc2 = {0.f,0.f}, acc3 = {0.f,0.f};
            CHALL
            qv = (acc0 + acc1) + (acc2 + acc3);

            int gb = __builtin_amdgcn_readfirstlane(__float_as_int(qv.x));
            kcur = ((gb >> 23) & 0xff) - 127;
            r    = __uint_as_float((unsigned)(127 - kcur) << 23);
        }
        if (i < 48) *reinterpret_cast<v2f*>(&uex[col]) = qv;
        if (i == 0) dks[1] = Dk;
    }
#undef CHALL
#undef CH
#undef EDECL
#undef EROWS

    __syncthreads();

    // ---- meeting point: log_norm = log(v_511 . q_511) + (Dk_f+Dk_b)*ln2 ----
    if (wave == 0) {
        v2f u = (i < 48) ? *reinterpret_cast<const v2f*>(&uex[col]) : (v2f){0.f, 0.f};
        float d = (i < 48) ? (qv.x * u.x + qv.y * u.y) : 0.f;
        #pragma unroll
        for (int off = 32; off; off >>= 1) d += __shfl_xor(d, off, 64);
        if (i == 0) {
            double ln = (double)(dks[0] + dks[1]) * 0.6931471805599453
                      + log((double)d);
            out[b] = (float)(ln - (double)(wps[0] + wps[1]));
        }
    }
}

extern "C" void kernel_launch(void* const* d_in, const int* in_sizes, int n_in,
                              void* d_out, int out_size, void* d_ws, size_t ws_size,
                              hipStream_t stream) {
    const float* inputs     = (const float*)d_in[0];
    const int*   labels_idx = (const int*)d_in[1];
    const float* trans      = (const float*)d_in[2];
    float*       out        = (float*)d_out;

    crf_fwd_kernel<<<dim3(Bb), dim3(128), 0, stream>>>(inputs, labels_idx, trans, out);
}

// Round 9
// 305.169 us; speedup vs baseline: 1.2898x; 1.2898x over previous
//
#include <hip/hip_runtime.h>
#include <math.h>

#define Bb 128
#define Tt 1024
#define Ll 96

typedef float v2f __attribute__((ext_vector_type(2)));
typedef float v4f __attribute__((ext_vector_type(4)));

// One block = one batch = TWO waves running INDEPENDENT halves of the chain
// (round 7): forward q_t = (E^T q_{t-1}) o w_t for t=1..511; backward
// v_{t-1} = E (v_t o w_t) for t=1023..512. Meeting point:
// log_norm = log(v_511 . q_511) + (Dk_f + Dk_b)*ln2.  512 serial steps.
//
// Round-9 fixes vs round 8:
//  * backward prefetch row t-7 (t-8 was an off-by-one: steady-state fed
//    exp(x_{t-1}) where x_t belonged -> absmax 32).
//  * q-reads software-pipelined in groups of 8 ds_read_b128: groups 0,1
//    issued before consuming group 0; group 2 issued while consuming group 1.
//    Round 8 ordered each read at its use -> ~950 cy/step of LDS latency
//    exposed (VALU issue measured ~550 cy, stall ~1000). With >=8 reads in
//    flight the compiler's counted lgkmcnt overlaps latency with FMAs.
// Accumulator grouping (acc_j collects l = j mod 4) is bit-identical to
// round 7 -> absmax must return to 0.0.
__global__ __launch_bounds__(128, 1)
__attribute__((amdgpu_waves_per_eu(1)))
void crf_fwd_kernel(
    const float* __restrict__ inputs,      // (B, T, L) fp32
    const int*   __restrict__ labels_idx,  // (B, T) int32
    const float* __restrict__ trans,       // (L, L) fp32
    float*       __restrict__ out)         // (B, 1) fp32
{
    const int b    = blockIdx.x;
    const int tid  = threadIdx.x;                    // 0..127
    const int wave = tid >> 6;
    const int i    = tid & 63;                       // lane
    const int col  = (2 * i < Ll) ? 2 * i : (Ll - 2); // clamp lanes 48..63

    __shared__ __align__(16) float qbuf[2][Ll];  // fwd double buffer (parity)
    __shared__ __align__(16) float sbuf[Ll];     // bwd single buffer
    __shared__ __align__(16) float uex[Ll];      // backward v_511
    __shared__ float wps[2];                     // per-wave score partials
    __shared__ int   dks[2];                     // per-wave Dk

    const float* xbase = inputs + (size_t)b * Tt * Ll;

    // ---- point_score + trans_score, split across both waves ----
    float ps = 0.f;
    {
        const int* lb = labels_idx + b * Tt;
        #pragma unroll 4
        for (int t = tid; t < Tt; t += 128) {
            int i0 = lb[t];
            ps += xbase[t * Ll + i0];
            if (t < Tt - 1) ps += trans[i0 * Ll + lb[t + 1]];
        }
        #pragma unroll
        for (int off = 32; off; off >>= 1) ps += __shfl_xor(ps, off, 64);
        if (i == 0) wps[wave] = ps;
    }

#define EROWS(X) \
    X(0)  X(1)  X(2)  X(3)  X(4)  X(5)  X(6)  X(7)  X(8)  X(9)  X(10) X(11) \
    X(12) X(13) X(14) X(15) X(16) X(17) X(18) X(19) X(20) X(21) X(22) X(23) \
    X(24) X(25) X(26) X(27) X(28) X(29) X(30) X(31) X(32) X(33) X(34) X(35) \
    X(36) X(37) X(38) X(39) X(40) X(41) X(42) X(43) X(44) X(45) X(46) X(47) \
    X(48) X(49) X(50) X(51) X(52) X(53) X(54) X(55) X(56) X(57) X(58) X(59) \
    X(60) X(61) X(62) X(63) X(64) X(65) X(66) X(67) X(68) X(69) X(70) X(71) \
    X(72) X(73) X(74) X(75) X(76) X(77) X(78) X(79) X(80) X(81) X(82) X(83) \
    X(84) X(85) X(86) X(87) X(88) X(89) X(90) X(91) X(92) X(93) X(94) X(95)

#define EDECL(n) v2f EE##n;

// one chunk: a 16B q-quad (already in regs) feeds 4 pk-FMAs via splats.
#define CHUNK(q4, n0, n1, n2, n3) { \
        acc0 += (v2f){q4.x, q4.x} * EE##n0; \
        acc1 += (v2f){q4.y, q4.y} * EE##n1; \
        acc2 += (v2f){q4.z, q4.z} * EE##n2; \
        acc3 += (v2f){q4.w, q4.w} * EE##n3; }

// pipelined matvec: issue reads >=8 ahead of consumption.
#define MATVEC(qp) \
        { \
        v4f q00=qp[0], q01=qp[1], q02=qp[2], q03=qp[3], \
            q04=qp[4], q05=qp[5], q06=qp[6], q07=qp[7]; \
        v4f q08=qp[8], q09=qp[9], q10=qp[10], q11=qp[11], \
            q12=qp[12], q13=qp[13], q14=qp[14], q15=qp[15]; \
        CHUNK(q00, 0,  1,  2,  3)   CHUNK(q01, 4,  5,  6,  7)  \
        CHUNK(q02, 8,  9,  10, 11)  CHUNK(q03, 12, 13, 14, 15) \
        CHUNK(q04, 16, 17, 18, 19)  CHUNK(q05, 20, 21, 22, 23) \
        CHUNK(q06, 24, 25, 26, 27)  CHUNK(q07, 28, 29, 30, 31) \
        v4f q16=qp[16], q17=qp[17], q18=qp[18], q19=qp[19], \
            q20=qp[20], q21=qp[21], q22=qp[22], q23=qp[23]; \
        CHUNK(q08, 32, 33, 34, 35)  CHUNK(q09, 36, 37, 38, 39) \
        CHUNK(q10, 40, 41, 42, 43)  CHUNK(q11, 44, 45, 46, 47) \
        CHUNK(q12, 48, 49, 50, 51)  CHUNK(q13, 52, 53, 54, 55) \
        CHUNK(q14, 56, 57, 58, 59)  CHUNK(q15, 60, 61, 62, 63) \
        CHUNK(q16, 64, 65, 66, 67)  CHUNK(q17, 68, 69, 70, 71) \
        CHUNK(q18, 72, 73, 74, 75)  CHUNK(q19, 76, 77, 78, 79) \
        CHUNK(q20, 80, 81, 82, 83)  CHUNK(q21, 84, 85, 86, 87) \
        CHUNK(q22, 88, 89, 90, 91)  CHUNK(q23, 92, 93, 94, 95) \
        }

    v2f qv;                // this wave's two owned state elements
    int Dk = 0;

    if (wave == 0) {
        // ================= FORWARD: t = 1..511 =================
        EROWS(EDECL)
        // column layout: EE_n = {E[n][col], E[n][col+1]}
#define EINIT(n) { v2f r_ = *reinterpret_cast<const v2f*>(&trans[(n) * Ll + col]); \
                   EE##n = (v2f){__expf(r_.x), __expf(r_.y)}; \
                   asm volatile("" ::: "memory"); }
        EROWS(EINIT)
#undef EINIT

        v2f x0 = *reinterpret_cast<const v2f*>(&xbase[col]);
        qv = (v2f){__expf(x0.x), __expf(x0.y)};
        if (i < 48) *reinterpret_cast<v2f*>(&qbuf[0][col]) = qv;
        asm volatile("" ::: "memory");
        int gb = __builtin_amdgcn_readfirstlane(__float_as_int(qv.x));
        int   kcur = ((gb >> 23) & 0xff) - 127;
        float r    = __uint_as_float((unsigned)(127 - kcur) << 23);

        v2f x1 = *reinterpret_cast<const v2f*>(&xbase[1 * Ll + col]);
        v2f ew = (v2f){__expf(x1.x), __expf(x1.y)};
        v2f x2 = *reinterpret_cast<const v2f*>(&xbase[2 * Ll + col]);
        v2f x3 = *reinterpret_cast<const v2f*>(&xbase[3 * Ll + col]);
        v2f x4 = *reinterpret_cast<const v2f*>(&xbase[4 * Ll + col]);
        v2f x5 = *reinterpret_cast<const v2f*>(&xbase[5 * Ll + col]);
        v2f x6 = *reinterpret_cast<const v2f*>(&xbase[6 * Ll + col]);
        v2f x7 = *reinterpret_cast<const v2f*>(&xbase[7 * Ll + col]);

        #pragma unroll 1
        for (int t = 1; t <= Tt / 2 - 1; ++t) {
            const int rp = (t - 1) & 1, wp = t & 1;
            Dk += kcur;
            v2f w = ew * r;

            const v4f* qp = reinterpret_cast<const v4f*>(&qbuf[rp][0]);
            v2f acc0 = {0.f,0.f}, acc1 = {0.f,0.f};
            v2f acc2 = {0.f,0.f}, acc3 = {0.f,0.f};
            MATVEC(qp)
            qv = ((acc0 + acc1) + (acc2 + acc3)) * w;

            if (i < 48) *reinterpret_cast<v2f*>(&qbuf[wp][col]) = qv;
            asm volatile("" ::: "memory");

            // off-path (fills write->read turnaround of next iteration)
            gb   = __builtin_amdgcn_readfirstlane(__float_as_int(qv.x));
            kcur = ((gb >> 23) & 0xff) - 127;
            r    = __uint_as_float((unsigned)(127 - kcur) << 23);
            ew   = (v2f){__expf(x2.x), __expf(x2.y)};
            x2 = x3; x3 = x4; x4 = x5; x5 = x6; x6 = x7;
            int row = t + 7; if (row > Tt - 1) row = Tt - 1;
            x7 = *reinterpret_cast<const v2f*>(&xbase[row * Ll + col]);
        }
        if (i == 0) dks[0] = Dk;
    } else {
        // ================= BACKWARD: t = 1023..512 =================
        // row layout: EE_n = {E[col][n], E[col+1][n]}
        EROWS(EDECL)
#define EINIT(n) { EE##n = (v2f){__expf(trans[col * Ll + (n)]), \
                                 __expf(trans[(col + 1) * Ll + (n)])}; \
                   asm volatile("" ::: "memory"); }
        EROWS(EINIT)
#undef EINIT

        qv = (v2f){1.f, 1.f};                  // v_1023
        int   kcur = 0;
        float r    = 1.f;

        v2f x1 = *reinterpret_cast<const v2f*>(&xbase[(Tt - 1) * Ll + col]);
        v2f ew = (v2f){__expf(x1.x), __expf(x1.y)};
        v2f x2 = *reinterpret_cast<const v2f*>(&xbase[(Tt - 2) * Ll + col]);
        v2f x3 = *reinterpret_cast<const v2f*>(&xbase[(Tt - 3) * Ll + col]);
        v2f x4 = *reinterpret_cast<const v2f*>(&xbase[(Tt - 4) * Ll + col]);
        v2f x5 = *reinterpret_cast<const v2f*>(&xbase[(Tt - 5) * Ll + col]);
        v2f x6 = *reinterpret_cast<const v2f*>(&xbase[(Tt - 6) * Ll + col]);
        v2f x7 = *reinterpret_cast<const v2f*>(&xbase[(Tt - 7) * Ll + col]);

        #pragma unroll 1
        for (int t = Tt - 1; t >= Tt / 2; --t) {
            Dk += kcur;
            v2f s = qv * (ew * r);             // s = v_t o w_t (pre-multiply)

            if (i < 48) *reinterpret_cast<v2f*>(&sbuf[col]) = s;
            asm volatile("" ::: "memory");

            // off-path between write and reads (absorbs the turnaround)
            ew = (v2f){__expf(x2.x), __expf(x2.y)};
            x2 = x3; x3 = x4; x4 = x5; x5 = x6; x6 = x7;
            int row = t - 7; if (row < 0) row = 0;   // FIXED: was t-8
            x7 = *reinterpret_cast<const v2f*>(&xbase[row * Ll + col]);

            const v4f* qp = reinterpret_cast<const v4f*>(&sbuf[0]);
            v2f acc0 = {0.f,0.f}, acc1 = {0.f,0.f};
            v2f acc2 = {0.f,0.f}, acc3 = {0.f,0.f};
            MATVEC(qp)
            qv = (acc0 + acc1) + (acc2 + acc3);

            int gb = __builtin_amdgcn_readfirstlane(__float_as_int(qv.x));
            kcur = ((gb >> 23) & 0xff) - 127;
            r    = __uint_as_float((unsigned)(127 - kcur) << 23);
        }
        if (i < 48) *reinterpret_cast<v2f*>(&uex[col]) = qv;
        if (i == 0) dks[1] = Dk;
    }
#undef MATVEC
#undef CHUNK
#undef EDECL
#undef EROWS

    __syncthreads();

    // ---- meeting point: log_norm = log(v_511 . q_511) + (Dk_f+Dk_b)*ln2 ----
    if (wave == 0) {
        v2f u = (i < 48) ? *reinterpret_cast<const v2f*>(&uex[col]) : (v2f){0.f, 0.f};
        float d = (i < 48) ? (qv.x * u.x + qv.y * u.y) : 0.f;
        #pragma unroll
        for (int off = 32; off; off >>= 1) d += __shfl_xor(d, off, 64);
        if (i == 0) {
            double ln = (double)(dks[0] + dks[1]) * 0.6931471805599453
                      + log((double)d);
            out[b] = (float)(ln - (double)(wps[0] + wps[1]));
        }
    }
}

extern "C" void kernel_launch(void* const* d_in, const int* in_sizes, int n_in,
                              void* d_out, int out_size, void* d_ws, size_t ws_size,
                              hipStream_t stream) {
    const float* inputs     = (const float*)d_in[0];
    const int*   labels_idx = (const int*)d_in[1];
    const float* trans      = (const float*)d_in[2];
    float*       out        = (float*)d_out;

    crf_fwd_kernel<<<dim3(Bb), dim3(128), 0, stream>>>(inputs, labels_idx, trans, out);
}